// Round 8
// baseline (227.345 us; speedup 1.0000x reference)
//
#include <hip/hip_runtime.h>
#include <hip/hip_bf16.h>
#include <stdint.h>

// MultiHeadAttention: B=2, S=2048, D=1024, H=16, DK=64, causal mask.
// R17 (resubmit after infra failure): qkv vmcnt retune + attn setprio (T5).
//  qkv: old schedule waited at ph4 with vmcnt(6), draining B(t+1).k1 only
//   3 phases after issue though it isn't consumed until t+1 ph3 (6 phases).
//   Weights per XCD (~6MB) exceed L2 (4MB) -> B loads are L3/HBM latency
//   (600-900cyc) -> ~300-600cyc stall per tile. New: ph2 vmcnt(10) (drains
//   t-1 ph1's B(t).k1, needed at t ph3) + ph4 vmcnt(8) (drains t-1 ph2-4 =
//   A(t+1)+B(t+1).k0, needed at t+1 ph1/ph3). All waits now 5-7 phases
//   after issue. Queue simulation verified prologue/t0/t1/steady/epilogue;
//   barrier counts wave-uniform (no hang vector).
//  attn: s_setprio(1) around QK and PV MFMA clusters (m191: +4-7% on
//   free-running attn; our 4-wave barrier-free loop matches that regime).
// o_gemm (R16 BK=64+swz), convert unchanged.

#define H_ 16
#define DM 1024
#define DK_ 64
#define BB 2
#define SS 2048
#define PSTR 72   // padded LDS stride (shorts) for P round-trip

typedef __bf16 bf16x8 __attribute__((ext_vector_type(8)));
typedef __bf16 bf16x2_t __attribute__((ext_vector_type(2)));
typedef float f32x4 __attribute__((ext_vector_type(4)));

#define GLOAD_LDS16(g, l)                                            \
  __builtin_amdgcn_global_load_lds(                                  \
      (__attribute__((address_space(1))) void*)(g),                  \
      (__attribute__((address_space(3))) void*)(l), 16, 0, 0)

__device__ __forceinline__ unsigned short f2bf_u(float f) {
  unsigned int u = __float_as_uint(f);
  u += 0x7fffu + ((u >> 16) & 1u);   // round-to-nearest-even
  return (unsigned short)(u >> 16);
}

__device__ __forceinline__ unsigned int pack_bf16(float a, float b) {
#if __has_builtin(__builtin_amdgcn_cvt_pk_bf16_f32)
  bf16x2_t v = __builtin_amdgcn_cvt_pk_bf16_f32(a, b);
  unsigned int u;
  __builtin_memcpy(&u, &v, 4);
  return u;
#else
  return (unsigned int)f2bf_u(a) | ((unsigned int)f2bf_u(b) << 16);
#endif
}

__device__ __forceinline__ float fexp2(float x) {
#if __has_builtin(__builtin_amdgcn_exp2f)
  return __builtin_amdgcn_exp2f(x);
#else
  return exp2f(x);
#endif
}

// ---------------------------------------------------------------- convert
struct Cvt {
  const float* s[7];
  unsigned short* d[7];
  int n[7];
};

__global__ __launch_bounds__(256) void convert_kernel(Cvt c) {
  const int y = blockIdx.y;
  const float* __restrict__ src = c.s[y];
  unsigned short* __restrict__ dst = c.d[y];
  const int nv = c.n[y] >> 2;
  for (int i = blockIdx.x * 256 + threadIdx.x; i < nv; i += 1024 * 256) {
    float4 v = *(const float4*)(src + (size_t)i * 4);
    ushort4 o;
    o.x = f2bf_u(v.x); o.y = f2bf_u(v.y); o.z = f2bf_u(v.z); o.w = f2bf_u(v.w);
    *(ushort4*)(dst + (size_t)i * 4) = o;
  }
}

// ---------------------------------------------------------------- qkv_gemm
// 256x256 tile, 8 waves (2Mx4N), BK=64, 8-phase counted-vmcnt schedule.
// R17 waits: ph2 vmcnt(10), ph4 vmcnt(8). Q scale folds 1/sqrt(64)*log2(e).
__global__ __launch_bounds__(512, 2) void qkv_gemm(
    const unsigned short* Qi, const unsigned short* Ki, const unsigned short* Vi,
    const unsigned short* Wq, const unsigned short* Wk, const unsigned short* Wv,
    const float* bq, const float* bk, const float* bv,
    unsigned short* Qf, unsigned short* Kf, unsigned short* Vf) {
  __shared__ unsigned short As[2 * 2 * 16 * 512];   // 64 KiB
  __shared__ unsigned short Bs[2 * 2 * 16 * 512];   // 64 KiB
  const int p = blockIdx.x;
  const int c = p & 7, idx = p >> 3;            // c = XCD, idx 0..23
  const int x = idx & 3, yy = (idx >> 2) & 1, z = idx >> 3;
  const int y = c * 2 + yy;
  const int m0 = y * 256, n0 = x * 256;
  const unsigned short* A = z == 0 ? Qi : (z == 1 ? Ki : Vi);
  const unsigned short* W = z == 0 ? Wq : (z == 1 ? Wk : Wv);
  const float* bias = z == 0 ? bq : (z == 1 ? bk : bv);
  // fold 1/sqrt(64) AND log2(e) into Q (attn uses exp2 directly)
  const float scale = z == 0 ? 0.1803368801111204f : 1.0f;

  const int tid = threadIdx.x;
  const int wave = tid >> 6, lane = tid & 63;
  const int lm = lane & 15, quad = lane >> 4;
  const int wr = wave >> 2, wc = wave & 3;      // wave grid 2M x 4N

  // --- staging addresses (global source carries the inverse swizzle) ---
  const int scs = 8 * ((lane & 3) ^ ((lane >> 3) & 3));
  const size_t asrc0 = (size_t)(m0 + wave * 16 + (lane >> 2)) * DM + scs;
  const size_t bsrc0 = (size_t)(n0 + wave * 16 + (lane >> 2)) * DM + scs;
  const int sdst = wave * 512 + lane * 8;       // shorts; +4096 for 2nd chunk

  // --- read offsets (shorts): swizzled column ---
  const int rcol = (quad * 8) ^ (((lm >> 1) & 3) * 8);
  const int aoff = wr * 8 * 512 + lm * 32 + rcol;
  const int boff = wc * 4 * 512 + lm * 32 + rcol;

  f32x4 acc[8][4];
#pragma unroll
  for (int i = 0; i < 8; ++i)
#pragma unroll
    for (int j = 0; j < 4; ++j) {
      f32x4 zz = {0.f, 0.f, 0.f, 0.f};
      acc[i][j] = zz;
    }

  auto stA = [&](int buf, int kh, int kt) {
    const unsigned short* s = A + asrc0 + (size_t)kt * 64 + kh * 32;
    unsigned short* d = As + buf * 16384 + kh * 8192 + sdst;
    GLOAD_LDS16(s, d);
    GLOAD_LDS16(s + (size_t)128 * DM, d + 4096);
  };
  auto stB = [&](int buf, int kh, int kt) {
    const unsigned short* s = W + bsrc0 + (size_t)kt * 64 + kh * 32;
    unsigned short* d = Bs + buf * 16384 + kh * 8192 + sdst;
    GLOAD_LDS16(s, d);
    GLOAD_LDS16(s + (size_t)128 * DM, d + 4096);
  };

  // prologue: t0 fully, t1 {A.k0, B.k0, A.k1}; then t0 resident.
  stA(0, 0, 0); stB(0, 0, 0); stA(0, 1, 0); stB(0, 1, 0);
  stA(1, 0, 1); stB(1, 0, 1); stA(1, 1, 1);
  asm volatile("s_waitcnt vmcnt(6)" ::: "memory");
  __builtin_amdgcn_s_barrier();

#define BARR __builtin_amdgcn_s_barrier()
#define SCHB __builtin_amdgcn_sched_barrier(0)
#define MFMA8(AF, B0_, B1_, J0, J1)                                          \
  __builtin_amdgcn_s_setprio(1);                                             \
  _Pragma("unroll")                                                          \
  for (int i = 0; i < 8; ++i) {                                              \
    acc[i][J0] = __builtin_amdgcn_mfma_f32_16x16x32_bf16(AF[i], B0_,         \
                                                         acc[i][J0], 0, 0, 0); \
    acc[i][J1] = __builtin_amdgcn_mfma_f32_16x16x32_bf16(AF[i], B1_,         \
                                                         acc[i][J1], 0, 0, 0); \
  }                                                                          \
  __builtin_amdgcn_s_setprio(0)

#pragma unroll 2
  for (int t = 0; t < 14; ++t) {
    const int buf = t & 1;
    const unsigned short* Ab = As + buf * 16384;
    const unsigned short* Bb = Bs + buf * 16384;
    // ---- ph1: kh0 fragments; stage (t+1).B.k1 (other buffer)
    bf16x8 a0[8], b0[4];
#pragma unroll
    for (int i = 0; i < 8; ++i)
      a0[i] = *(const bf16x8*)(Ab + aoff + i * 512);
#pragma unroll
    for (int j = 0; j < 4; ++j)
      b0[j] = *(const bf16x8*)(Bb + boff + j * 512);
    stB(buf ^ 1, 1, t + 1);
    BARR; SCHB;
    MFMA8(a0, b0[0], b0[1], 0, 1);
    SCHB; BARR;
    // ---- ph2: stage (t+2).A.k0 (this buffer; a0 consumed in ph1).
    // vmcnt(10): drains t-1 ph1's B(t).k1 — consumed by ph3's ds_reads.
    stA(buf, 0, t + 2);
    asm volatile("s_waitcnt vmcnt(10)" ::: "memory");
    BARR; SCHB;
    MFMA8(a0, b0[2], b0[3], 2, 3);
    SCHB; BARR;
    // ---- ph3: kh1 fragments; stage (t+2).B.k0 (b0 consumed by ph2)
    bf16x8 a1[8], b1[4];
#pragma unroll
    for (int i = 0; i < 8; ++i)
      a1[i] = *(const bf16x8*)(Ab + 8192 + aoff + i * 512);
#pragma unroll
    for (int j = 0; j < 4; ++j)
      b1[j] = *(const bf16x8*)(Bb + 8192 + boff + j * 512);
    stB(buf, 0, t + 2);
    BARR; SCHB;
    MFMA8(a1, b1[0], b1[1], 0, 1);
    SCHB; BARR;
    // ---- ph4: stage (t+2).A.k1 (a1 consumed in ph3).
    // vmcnt(8): drains everything older than this tile's issues =
    // A(t+1).k0 (t-1 ph2), B(t+1).k0 (t-1 ph3), A(t+1).k1 (t-1 ph4) —
    // exactly what t+1 ph1/ph3 need. B(t+1).k1 guarded by t+1 ph2.
    stA(buf, 1, t + 2);
    asm volatile("s_waitcnt vmcnt(8)" ::: "memory");
    BARR; SCHB;
    MFMA8(a1, b1[2], b1[3], 2, 3);
    SCHB; BARR;
  }

  // epilogue: stage the last missing half, drain, compute tiles 14 & 15.
  stB(1, 1, 15);
  asm volatile("s_waitcnt vmcnt(0)" ::: "memory");
  __builtin_amdgcn_s_barrier();
#pragma unroll
  for (int tt = 0; tt < 2; ++tt) {              // tile 14 (buf0), 15 (buf1)
    const unsigned short* Ab = As + tt * 16384;
    const unsigned short* Bb = Bs + tt * 16384;
#pragma unroll
    for (int kh = 0; kh < 2; ++kh) {
      bf16x8 a2[8], b2[4];
#pragma unroll
      for (int i = 0; i < 8; ++i)
        a2[i] = *(const bf16x8*)(Ab + kh * 8192 + aoff + i * 512);
#pragma unroll
      for (int j = 0; j < 4; ++j)
        b2[j] = *(const bf16x8*)(Bb + kh * 8192 + boff + j * 512);
#pragma unroll
      for (int i = 0; i < 8; ++i)
#pragma unroll
        for (int j = 0; j < 4; ++j)
          acc[i][j] = __builtin_amdgcn_mfma_f32_16x16x32_bf16(
              a2[i], b2[j], acc[i][j], 0, 0, 0);
    }
  }
#undef MFMA8
#undef SCHB
#undef BARR

  // epilogue: per-wave 128x64 output at (m0 + wr*128, n0 + wc*64).
  if (z == 2) {
#pragma unroll
    for (int j = 0; j < 4; ++j) {
      int gn = n0 + wc * 64 + j * 16 + lm;
      float bv_ = bias[gn];
      int h2 = gn >> 6, dk = gn & 63;
      int a = dk >> 4, ln = dk & 15;
#pragma unroll
      for (int i = 0; i < 8; ++i) {
        int s0 = m0 + wr * 128 + i * 16 + quad * 4;   // 4 consecutive s
        int b2 = s0 >> 11, sl = s0 & 2047;
        int kt2 = sl >> 6, cc2 = (sl >> 5) & 1, qk = (sl >> 3) & 3, j0 = sl & 7;
        size_t base =
            ((size_t)(((b2 * 16 + h2) * 32 + kt2) * 4 + a) * 2 + cc2) * 512 +
            (qk * 16 + ln) * 8 + j0;
        uint2 w;
        w.x = pack_bf16(acc[i][j][0] + bv_, acc[i][j][1] + bv_);
        w.y = pack_bf16(acc[i][j][2] + bv_, acc[i][j][3] + bv_);
        *(uint2*)(Vf + base) = w;
      }
    }
  } else {
    unsigned short* out = z == 0 ? Qf : Kf;
#pragma unroll
    for (int j = 0; j < 4; ++j) {
      int gn = n0 + wc * 64 + j * 16 + lm;
      float bv_ = bias[gn];
      int h2 = gn >> 6, d64 = gn & 63;
      int cc2 = (d64 >> 5) & 1, qk = (d64 >> 3) & 3, jjq = d64 & 7;
#pragma unroll
      for (int i = 0; i < 8; ++i)
#pragma unroll
        for (int r = 0; r < 4; ++r) {
          int gm = m0 + wr * 128 + i * 16 + quad * 4 + r;
          int b2 = gm >> 11, sl = gm & 2047;
          size_t base =
              ((size_t)((b2 * 16 + h2) * 128 + (sl >> 4)) * 2 + cc2) * 512 +
              (qk * 16 + (sl & 15)) * 8 + jjq;
          out[base] = f2bf_u((acc[i][j][r] + bv_) * scale);
        }
    }
  }
}

// ---------------------------------------------------------------- o_gemm
// R16: 128x64 tile, BK=64 (16 barriers), 4 waves (2Mx2N), chunked 16x32 LDS
// with the qkv-verified T2 swizzle pair. Compiler-drained dbuf.
__global__ __launch_bounds__(256) void o_gemm(
    const unsigned short* Ctx, const unsigned short* Wo, const float* bo,
    float* out) {
  __shared__ unsigned short As[2 * 2 * 8 * 512];   // 32 KiB
  __shared__ unsigned short Bs[2 * 2 * 4 * 512];   // 16 KiB
  const int p = blockIdx.x;
  const int c = p & 7, j0 = p >> 3;              // j0 0..63
  const int x = j0 & 15, yy = j0 >> 4;           // x 0..15, yy 0..3
  const int y = c * 4 + yy;
  const int m0 = y * 128, n0 = x * 64;
  const int tid = threadIdx.x;
  const int wave = tid >> 6, lane = tid & 63;
  const int lm = lane & 15, quad = lane >> 4;
  const int wm = (wave >> 1) * 64, wn = (wave & 1) * 32;

  // staging: inverse-swizzled global source, linear LDS dest (qkv pattern)
  const int scs = 8 * ((lane & 3) ^ ((lane >> 3) & 3));
  const int srow = lane >> 2;
  const size_t aSrc0 = (size_t)(m0 + wave * 32 + srow) * DM + scs;
  const size_t bSrc0 = (size_t)(n0 + wave * 16 + srow) * DM + scs;
  const int aDst0 = wave * 2 * 512 + lane * 8;   // chunks wave*2, wave*2+1
  const int bDst0 = wave * 512 + lane * 8;       // chunk wave

  // read offsets (swizzled column), chunk = row/16
  const int rcol = (quad * 8) ^ (((lm >> 1) & 3) * 8);
  const int aoff = (wm >> 4) * 512 + lm * 32 + rcol;  // + i*512 + kh*4096 + buf*8192
  const int boff = (wn >> 4) * 512 + lm * 32 + rcol;  // + j*512 + kh*2048 + buf*4096

  f32x4 acc[4][2];
#pragma unroll
  for (int i = 0; i < 4; ++i)
#pragma unroll
    for (int j = 0; j < 2; ++j) {
      f32x4 z = {0.f, 0.f, 0.f, 0.f};
      acc[i][j] = z;
    }

  auto stAB = [&](int buf, int kt) {
#pragma unroll
    for (int kh = 0; kh < 2; ++kh) {
      const unsigned short* sa = Ctx + aSrc0 + (size_t)kt * 64 + kh * 32;
      unsigned short* da = As + buf * 8192 + kh * 4096 + aDst0;
      GLOAD_LDS16(sa, da);
      GLOAD_LDS16(sa + (size_t)16 * DM, da + 512);
      const unsigned short* sb = Wo + bSrc0 + (size_t)kt * 64 + kh * 32;
      GLOAD_LDS16(sb, Bs + buf * 4096 + kh * 2048 + bDst0);
    }
  };

  stAB(0, 0);                                   // stage tile 0 into buf 0
  for (int kt = 0; kt < DM / 64; ++kt) {
    __syncthreads();                            // tile kt resident (drained)
    const int buf = kt & 1;
    if (kt + 1 < DM / 64) stAB(buf ^ 1, kt + 1);
    const unsigned short* Ac = As + buf * 8192;
    const unsigned short* Bc = Bs + buf * 4096;
#pragma unroll
    for (int kh = 0; kh < 2; ++kh) {
      bf16x8 af[4], bf_[2];
#pragma unroll
      for (int i = 0; i < 4; ++i)
        af[i] = *(const bf16x8*)(Ac + kh * 4096 + aoff + i * 512);
#pragma unroll
      for (int j = 0; j < 2; ++j)
        bf_[j] = *(const bf16x8*)(Bc + kh * 2048 + boff + j * 512);
#pragma unroll
      for (int i = 0; i < 4; ++i)
#pragma unroll
        for (int j = 0; j < 2; ++j)
          acc[i][j] = __builtin_amdgcn_mfma_f32_16x16x32_bf16(
              af[i], bf_[j], acc[i][j], 0, 0, 0);
    }
  }

#pragma unroll
  for (int j = 0; j < 2; ++j) {
    int gn = n0 + wn + j * 16 + lm;
    float bv_ = bo[gn];
#pragma unroll
    for (int i = 0; i < 4; ++i)
#pragma unroll
      for (int r = 0; r < 4; ++r) {
        int gm = m0 + wm + i * 16 + quad * 4 + r;
        out[(size_t)gm * DM + gn] = acc[i][j][r] + bv_;
      }
  }
}

// ------------------------------------------------------------- attention
// kt-split waves + K register double-buffer (R16) + T5 setprio around
// MFMA clusters. Grid 1024 = 32 bh x 32 qt, LPT order, 2 blocks/CU.
__global__ __launch_bounds__(256, 2) void attn_kernel(
    const unsigned short* __restrict__ Qf, const unsigned short* __restrict__ Kf,
    const unsigned short* __restrict__ Vf, unsigned short* __restrict__ Ctx) {
  __shared__ float Rs[4][64][21];              // 21-pad: conflict-free reduce
  __shared__ unsigned short Ps[4][16 * PSTR];  // per-wave P round-trip
  const int p = blockIdx.x;
  const int bh = p & 31, qt = 31 - (p >> 5);   // LPT: long blocks first
  const int b = bh >> 4, h = bh & 15;
  const int tid = threadIdx.x, wave = tid >> 6, lane = tid & 63;
  const int lm = lane & 15, quad = lane >> 4;

  const int qbase0 = qt * 64;
  const int nkw = qt + 1;

  const unsigned short* Kb = Kf + (size_t)bh * 256 * 512;
  const unsigned short* Vb = Vf + (size_t)bh * 256 * 512;
  unsigned short* Pw = Ps[wave];

  bf16x8 onesf;
  {
    unsigned short ob[8] = {0x3F80, 0x3F80, 0x3F80, 0x3F80,
                            0x3F80, 0x3F80, 0x3F80, 0x3F80};
    __builtin_memcpy(&onesf, ob, 16);
  }

  // Q for all 4 frags of this block's q-tile
  bf16x8 qf[4][2];
#pragma unroll
  for (int f = 0; f < 4; ++f)
#pragma unroll
    for (int c = 0; c < 2; ++c)
      qf[f][c] = *(const bf16x8*)(Qf +
          ((size_t)(bh * 128 + qt * 4 + f) * 2 + c) * 512 + lane * 8);

  f32x4 oacc[4][4];                            // [frag][a]
#pragma unroll
  for (int f = 0; f < 4; ++f)
#pragma unroll
    for (int a = 0; a < 4; ++a) {
      f32x4 z = {0.f, 0.f, 0.f, 0.f};
      oacc[f][a] = z;
    }
  f32x4 lacc[4];
#pragma unroll
  for (int f = 0; f < 4; ++f) {
    f32x4 z = {0.f, 0.f, 0.f, 0.f};
    lacc[f] = z;
  }

  auto loadK = [&](bf16x8 (&kf)[4][2], int kt) {
#pragma unroll
    for (int ik = 0; ik < 4; ++ik)
#pragma unroll
      for (int c = 0; c < 2; ++c)
        kf[ik][c] = *(const bf16x8*)(Kb +
            ((size_t)(kt * 4 + ik) * 2 + c) * 512 + lane * 8);
  };

  auto computeKt = [&](bf16x8 (&kf)[4][2], int kt, bool last) {
    bf16x8 vf[4][2];                           // issue V loads first
#pragma unroll
    for (int a = 0; a < 4; ++a)
#pragma unroll
      for (int c = 0; c < 2; ++c)
        vf[a][c] = *(const bf16x8*)(Vb +
            ((size_t)(kt * 8 + a * 2 + c)) * 512 + lane * 8);

#pragma unroll
    for (int f = 0; f < 4; ++f) {
      f32x4 s[4];
      __builtin_amdgcn_s_setprio(1);
#pragma unroll
      for (int ik = 0; ik < 4; ++ik) {
        f32x4 zz = {0.f, 0.f, 0.f, 0.f};
        zz = __builtin_amdgcn_mfma_f32_16x16x32_bf16(kf[ik][0], qf[f][0], zz,
                                                     0, 0, 0);
        s[ik] = __builtin_amdgcn_mfma_f32_16x16x32_bf16(kf[ik][1], qf[f][1],
                                                        zz, 0, 0, 0);
      }
      __builtin_amdgcn_s_setprio(0);
      if (last) {
        int qg = qbase0 + f * 16 + lm;
#pragma unroll
        for (int ik = 0; ik < 4; ++ik)
#pragma unroll
          for (int r = 0; r < 4; ++r) {
            int kg = kt * 64 + ik * 16 + quad * 4 + r;
            if (kg > qg) s[ik][r] = -1e30f;
          }
      }
#pragma unroll
      for (int ik = 0; ik < 4; ++ik) {
        float p0 = fexp2(s[ik][0]);
        float p1 = fexp2(s[ik][1]);
        float p2 = fexp2(s[ik][2]);
        float p3 = fexp2(s[ik][3]);
        uint2 w;
        w.x = pack_bf16(p0, p1);
        w.y = pack_bf16(p2, p3);
        *(uint2*)(Pw + lm * PSTR + ik * 16 + quad * 4) = w;
      }
      bf16x8 pf[2];
#pragma unroll
      for (int c = 0; c < 2; ++c)
        pf[c] = *(const bf16x8*)(Pw + lm * PSTR + c * 32 + quad * 8);
      __builtin_amdgcn_s_setprio(1);
#pragma unroll
      for (int a = 0; a < 4; ++a) {
        oacc[f][a] = __builtin_amdgcn_mfma_f32_16x16x32_bf16(pf[0], vf[a][0],
                                                             oacc[f][a], 0, 0, 0);
        oacc[f][a] = __builtin_amdgcn_mfma_f32_16x16x32_bf16(pf[1], vf[a][1],
                                                             oacc[f][a], 0, 0, 0);
      }
      lacc[f] = __builtin_amdgcn_mfma_f32_16x16x32_bf16(pf[0], onesf, lacc[f],
                                                        0, 0, 0);
      lacc[f] = __builtin_amdgcn_mfma_f32_16x16x32_bf16(pf[1], onesf, lacc[f],
                                                        0, 0, 0);
      __builtin_amdgcn_s_setprio(0);
    }
  };

  bf16x8 kA[4][2], kB[4][2];
  if (wave < nkw) loadK(kA, wave);
  for (int kt = wave; kt < nkw; kt += 8) {
    if (kt + 4 < nkw) loadK(kB, kt + 4);
    computeKt(kA, kt, kt == nkw - 1);
    if (kt + 4 < nkw) {
      if (kt + 8 < nkw) loadK(kA, kt + 8);
      computeKt(kB, kt + 4, kt + 4 == nkw - 1);
    }
  }

  // cross-wave reduce + store, frag-sequential (reuses one buffer).
  const size_t obase = (size_t)(b * SS) * DM + (size_t)h * DK_;
#pragma unroll
  for (int f = 0; f < 4; ++f) {
    __syncthreads();                           // prev round's reads done
#pragma unroll
    for (int a = 0; a < 4; ++a)
#pragma unroll
      for (int r = 0; r < 4; ++r)
        Rs[wave][lane][a * 4 + r] = oacc[f][a][r];
#pragma unroll
    for (int r = 0; r < 4; ++r)
      Rs[wave][lane][16 + r] = lacc[f][r];
    __syncthreads();
    // wave w stores column block a = w of frag f
#pragma unroll
    for (int r = 0; r < 4; ++r) {
      float ov = Rs[0][lane][wave * 4 + r] + Rs[1][lane][wave * 4 + r] +
                 Rs[2][lane][wave * 4 + r] + Rs[3][lane][wave * 4 + r];
      float lv = Rs[0][lane][16 + r] + Rs[1][lane][16 + r] +
                 Rs[2][lane][16 + r] + Rs[3][lane][16 + r];
      int qg = qbase0 + f * 16 + quad * 4 + r;
      Ctx[obase + (size_t)qg * DM + wave * 16 + lm] = f2bf_u(ov / lv);
    }
  }
}

// ---------------------------------------------------------------- launch
extern "C" void kernel_launch(void* const* d_in, const int* in_sizes, int n_in,
                              void* d_out, int out_size, void* d_ws, size_t ws_size,
                              hipStream_t stream) {
  const float* q = (const float*)d_in[0];
  const float* k = (const float*)d_in[1];
  const float* v = (const float*)d_in[2];
  // d_in[3] = mask (fixed causal tril) — handled analytically
  const float* Wq = (const float*)d_in[4];
  const float* bq = (const float*)d_in[5];
  const float* Wk = (const float*)d_in[6];
  const float* bk = (const float*)d_in[7];
  const float* Wv = (const float*)d_in[8];
  const float* bv = (const float*)d_in[9];
  const float* Wo = (const float*)d_in[10];
  const float* bo = (const float*)d_in[11];

  const size_t NX = (size_t)BB * SS * DM;  // 4194304 shorts
  const size_t NW = (size_t)DM * DM;       // 1048576 shorts
  unsigned short* ws = (unsigned short*)d_ws;
  unsigned short* Qi = ws;
  unsigned short* Ki = Qi + NX;
  unsigned short* Vi = Ki + NX;
  unsigned short* Wqb = Vi + NX;
  unsigned short* Wkb = Wqb + NW;
  unsigned short* Wvb = Wkb + NW;
  unsigned short* Wob = Wvb + NW;
  unsigned short* Qfr = Wob + NW;
  unsigned short* Kfr = Qfr + NX;
  unsigned short* Vfr = Kfr + NX;
  unsigned short* Ctx = Vfr + NX;

  Cvt c;
  c.s[0] = q; c.s[1] = k; c.s[2] = v; c.s[3] = Wq; c.s[4] = Wk; c.s[5] = Wv; c.s[6] = Wo;
  c.d[0] = Qi; c.d[1] = Ki; c.d[2] = Vi; c.d[3] = Wqb; c.d[4] = Wkb; c.d[5] = Wvb; c.d[6] = Wob;
  c.n[0] = c.n[1] = c.n[2] = (int)NX;
  c.n[3] = c.n[4] = c.n[5] = c.n[6] = (int)NW;

  convert_kernel<<<dim3(1024, 7), dim3(256), 0, stream>>>(c);
  qkv_gemm<<<dim3(192), dim3(512), 0, stream>>>(Qi, Ki, Vi, Wqb, Wkb, Wvb,
                                                bq, bk, bv, Qfr, Kfr, Vfr);
  attn_kernel<<<dim3(1024), dim3(256), 0, stream>>>(Qfr, Kfr, Vfr, Ctx);
  o_gemm<<<dim3(512), dim3(256), 0, stream>>>(Ctx, Wob, bo, (float*)d_out);
}

// Round 9
// 224.293 us; speedup vs baseline: 1.0136x; 1.0136x over previous
//
#include <hip/hip_runtime.h>
#include <hip/hip_bf16.h>
#include <stdint.h>

// MultiHeadAttention: B=2, S=2048, D=1024, H=16, DK=64, causal mask.
// R18: attn intra-kt software pipeline (T15-style, depth 2).
//  R17 post-mortem: vmcnt retune null -> qkv is AT the m248 K=1024 anchor
//  (841 TF/active-CU); parked. attn's stall (by elimination after K-dbuf
//  null + setprio null) is the serial per-fragment chain QK->exp->LDS->PV.
//  New computeKt interleaves fragments: QK(f+1)+exp(f+1) issued adjacent to
//  PV(f) so MFMA and VALU/trans pipes overlap; P round-trip uses TWO
//  alternating per-wave LDS buffers (Pw0/Pw1) to break the write-after-read
//  lgkm serialization. Bitwise-identical math. attn setprio removed (null).
// qkv_gemm (R17 waits, conflicts=0), o_gemm (R16), convert unchanged.

#define H_ 16
#define DM 1024
#define DK_ 64
#define BB 2
#define SS 2048
#define PSTR 72   // padded LDS stride (shorts) for P round-trip

typedef __bf16 bf16x8 __attribute__((ext_vector_type(8)));
typedef __bf16 bf16x2_t __attribute__((ext_vector_type(2)));
typedef float f32x4 __attribute__((ext_vector_type(4)));

#define GLOAD_LDS16(g, l)                                            \
  __builtin_amdgcn_global_load_lds(                                  \
      (__attribute__((address_space(1))) void*)(g),                  \
      (__attribute__((address_space(3))) void*)(l), 16, 0, 0)

__device__ __forceinline__ unsigned short f2bf_u(float f) {
  unsigned int u = __float_as_uint(f);
  u += 0x7fffu + ((u >> 16) & 1u);   // round-to-nearest-even
  return (unsigned short)(u >> 16);
}

__device__ __forceinline__ unsigned int pack_bf16(float a, float b) {
#if __has_builtin(__builtin_amdgcn_cvt_pk_bf16_f32)
  bf16x2_t v = __builtin_amdgcn_cvt_pk_bf16_f32(a, b);
  unsigned int u;
  __builtin_memcpy(&u, &v, 4);
  return u;
#else
  return (unsigned int)f2bf_u(a) | ((unsigned int)f2bf_u(b) << 16);
#endif
}

__device__ __forceinline__ float fexp2(float x) {
#if __has_builtin(__builtin_amdgcn_exp2f)
  return __builtin_amdgcn_exp2f(x);
#else
  return exp2f(x);
#endif
}

// ---------------------------------------------------------------- convert
struct Cvt {
  const float* s[7];
  unsigned short* d[7];
  int n[7];
};

__global__ __launch_bounds__(256) void convert_kernel(Cvt c) {
  const int y = blockIdx.y;
  const float* __restrict__ src = c.s[y];
  unsigned short* __restrict__ dst = c.d[y];
  const int nv = c.n[y] >> 2;
  for (int i = blockIdx.x * 256 + threadIdx.x; i < nv; i += 1024 * 256) {
    float4 v = *(const float4*)(src + (size_t)i * 4);
    ushort4 o;
    o.x = f2bf_u(v.x); o.y = f2bf_u(v.y); o.z = f2bf_u(v.z); o.w = f2bf_u(v.w);
    *(ushort4*)(dst + (size_t)i * 4) = o;
  }
}

// ---------------------------------------------------------------- qkv_gemm
// 256x256 tile, 8 waves (2Mx4N), BK=64, 8-phase counted-vmcnt schedule.
// (R17 waits; at m248 K=1024 anchor — parked.) Q scale folds
// 1/sqrt(64) AND log2(e).
__global__ __launch_bounds__(512, 2) void qkv_gemm(
    const unsigned short* Qi, const unsigned short* Ki, const unsigned short* Vi,
    const unsigned short* Wq, const unsigned short* Wk, const unsigned short* Wv,
    const float* bq, const float* bk, const float* bv,
    unsigned short* Qf, unsigned short* Kf, unsigned short* Vf) {
  __shared__ unsigned short As[2 * 2 * 16 * 512];   // 64 KiB
  __shared__ unsigned short Bs[2 * 2 * 16 * 512];   // 64 KiB
  const int p = blockIdx.x;
  const int c = p & 7, idx = p >> 3;            // c = XCD, idx 0..23
  const int x = idx & 3, yy = (idx >> 2) & 1, z = idx >> 3;
  const int y = c * 2 + yy;
  const int m0 = y * 256, n0 = x * 256;
  const unsigned short* A = z == 0 ? Qi : (z == 1 ? Ki : Vi);
  const unsigned short* W = z == 0 ? Wq : (z == 1 ? Wk : Wv);
  const float* bias = z == 0 ? bq : (z == 1 ? bk : bv);
  // fold 1/sqrt(64) AND log2(e) into Q (attn uses exp2 directly)
  const float scale = z == 0 ? 0.1803368801111204f : 1.0f;

  const int tid = threadIdx.x;
  const int wave = tid >> 6, lane = tid & 63;
  const int lm = lane & 15, quad = lane >> 4;
  const int wr = wave >> 2, wc = wave & 3;      // wave grid 2M x 4N

  // --- staging addresses (global source carries the inverse swizzle) ---
  const int scs = 8 * ((lane & 3) ^ ((lane >> 3) & 3));
  const size_t asrc0 = (size_t)(m0 + wave * 16 + (lane >> 2)) * DM + scs;
  const size_t bsrc0 = (size_t)(n0 + wave * 16 + (lane >> 2)) * DM + scs;
  const int sdst = wave * 512 + lane * 8;       // shorts; +4096 for 2nd chunk

  // --- read offsets (shorts): swizzled column ---
  const int rcol = (quad * 8) ^ (((lm >> 1) & 3) * 8);
  const int aoff = wr * 8 * 512 + lm * 32 + rcol;
  const int boff = wc * 4 * 512 + lm * 32 + rcol;

  f32x4 acc[8][4];
#pragma unroll
  for (int i = 0; i < 8; ++i)
#pragma unroll
    for (int j = 0; j < 4; ++j) {
      f32x4 zz = {0.f, 0.f, 0.f, 0.f};
      acc[i][j] = zz;
    }

  auto stA = [&](int buf, int kh, int kt) {
    const unsigned short* s = A + asrc0 + (size_t)kt * 64 + kh * 32;
    unsigned short* d = As + buf * 16384 + kh * 8192 + sdst;
    GLOAD_LDS16(s, d);
    GLOAD_LDS16(s + (size_t)128 * DM, d + 4096);
  };
  auto stB = [&](int buf, int kh, int kt) {
    const unsigned short* s = W + bsrc0 + (size_t)kt * 64 + kh * 32;
    unsigned short* d = Bs + buf * 16384 + kh * 8192 + sdst;
    GLOAD_LDS16(s, d);
    GLOAD_LDS16(s + (size_t)128 * DM, d + 4096);
  };

  // prologue: t0 fully, t1 {A.k0, B.k0, A.k1}; then t0 resident.
  stA(0, 0, 0); stB(0, 0, 0); stA(0, 1, 0); stB(0, 1, 0);
  stA(1, 0, 1); stB(1, 0, 1); stA(1, 1, 1);
  asm volatile("s_waitcnt vmcnt(6)" ::: "memory");
  __builtin_amdgcn_s_barrier();

#define BARR __builtin_amdgcn_s_barrier()
#define SCHB __builtin_amdgcn_sched_barrier(0)
#define MFMA8(AF, B0_, B1_, J0, J1)                                          \
  __builtin_amdgcn_s_setprio(1);                                             \
  _Pragma("unroll")                                                          \
  for (int i = 0; i < 8; ++i) {                                              \
    acc[i][J0] = __builtin_amdgcn_mfma_f32_16x16x32_bf16(AF[i], B0_,         \
                                                         acc[i][J0], 0, 0, 0); \
    acc[i][J1] = __builtin_amdgcn_mfma_f32_16x16x32_bf16(AF[i], B1_,         \
                                                         acc[i][J1], 0, 0, 0); \
  }                                                                          \
  __builtin_amdgcn_s_setprio(0)

#pragma unroll 2
  for (int t = 0; t < 14; ++t) {
    const int buf = t & 1;
    const unsigned short* Ab = As + buf * 16384;
    const unsigned short* Bb = Bs + buf * 16384;
    // ---- ph1: kh0 fragments; stage (t+1).B.k1 (other buffer)
    bf16x8 a0[8], b0[4];
#pragma unroll
    for (int i = 0; i < 8; ++i)
      a0[i] = *(const bf16x8*)(Ab + aoff + i * 512);
#pragma unroll
    for (int j = 0; j < 4; ++j)
      b0[j] = *(const bf16x8*)(Bb + boff + j * 512);
    stB(buf ^ 1, 1, t + 1);
    BARR; SCHB;
    MFMA8(a0, b0[0], b0[1], 0, 1);
    SCHB; BARR;
    // ---- ph2: stage (t+2).A.k0 (this buffer; a0 consumed in ph1).
    stA(buf, 0, t + 2);
    asm volatile("s_waitcnt vmcnt(10)" ::: "memory");
    BARR; SCHB;
    MFMA8(a0, b0[2], b0[3], 2, 3);
    SCHB; BARR;
    // ---- ph3: kh1 fragments; stage (t+2).B.k0 (b0 consumed by ph2)
    bf16x8 a1[8], b1[4];
#pragma unroll
    for (int i = 0; i < 8; ++i)
      a1[i] = *(const bf16x8*)(Ab + 8192 + aoff + i * 512);
#pragma unroll
    for (int j = 0; j < 4; ++j)
      b1[j] = *(const bf16x8*)(Bb + 8192 + boff + j * 512);
    stB(buf, 0, t + 2);
    BARR; SCHB;
    MFMA8(a1, b1[0], b1[1], 0, 1);
    SCHB; BARR;
    // ---- ph4: stage (t+2).A.k1 (a1 consumed in ph3).
    stA(buf, 1, t + 2);
    asm volatile("s_waitcnt vmcnt(8)" ::: "memory");
    BARR; SCHB;
    MFMA8(a1, b1[2], b1[3], 2, 3);
    SCHB; BARR;
  }

  // epilogue: stage the last missing half, drain, compute tiles 14 & 15.
  stB(1, 1, 15);
  asm volatile("s_waitcnt vmcnt(0)" ::: "memory");
  __builtin_amdgcn_s_barrier();
#pragma unroll
  for (int tt = 0; tt < 2; ++tt) {              // tile 14 (buf0), 15 (buf1)
    const unsigned short* Ab = As + tt * 16384;
    const unsigned short* Bb = Bs + tt * 16384;
#pragma unroll
    for (int kh = 0; kh < 2; ++kh) {
      bf16x8 a2[8], b2[4];
#pragma unroll
      for (int i = 0; i < 8; ++i)
        a2[i] = *(const bf16x8*)(Ab + kh * 8192 + aoff + i * 512);
#pragma unroll
      for (int j = 0; j < 4; ++j)
        b2[j] = *(const bf16x8*)(Bb + kh * 8192 + boff + j * 512);
#pragma unroll
      for (int i = 0; i < 8; ++i)
#pragma unroll
        for (int j = 0; j < 4; ++j)
          acc[i][j] = __builtin_amdgcn_mfma_f32_16x16x32_bf16(
              a2[i], b2[j], acc[i][j], 0, 0, 0);
    }
  }
#undef MFMA8
#undef SCHB
#undef BARR

  // epilogue: per-wave 128x64 output at (m0 + wr*128, n0 + wc*64).
  if (z == 2) {
#pragma unroll
    for (int j = 0; j < 4; ++j) {
      int gn = n0 + wc * 64 + j * 16 + lm;
      float bv_ = bias[gn];
      int h2 = gn >> 6, dk = gn & 63;
      int a = dk >> 4, ln = dk & 15;
#pragma unroll
      for (int i = 0; i < 8; ++i) {
        int s0 = m0 + wr * 128 + i * 16 + quad * 4;   // 4 consecutive s
        int b2 = s0 >> 11, sl = s0 & 2047;
        int kt2 = sl >> 6, cc2 = (sl >> 5) & 1, qk = (sl >> 3) & 3, j0 = sl & 7;
        size_t base =
            ((size_t)(((b2 * 16 + h2) * 32 + kt2) * 4 + a) * 2 + cc2) * 512 +
            (qk * 16 + ln) * 8 + j0;
        uint2 w;
        w.x = pack_bf16(acc[i][j][0] + bv_, acc[i][j][1] + bv_);
        w.y = pack_bf16(acc[i][j][2] + bv_, acc[i][j][3] + bv_);
        *(uint2*)(Vf + base) = w;
      }
    }
  } else {
    unsigned short* out = z == 0 ? Qf : Kf;
#pragma unroll
    for (int j = 0; j < 4; ++j) {
      int gn = n0 + wc * 64 + j * 16 + lm;
      float bv_ = bias[gn];
      int h2 = gn >> 6, d64 = gn & 63;
      int cc2 = (d64 >> 5) & 1, qk = (d64 >> 3) & 3, jjq = d64 & 7;
#pragma unroll
      for (int i = 0; i < 8; ++i)
#pragma unroll
        for (int r = 0; r < 4; ++r) {
          int gm = m0 + wr * 128 + i * 16 + quad * 4 + r;
          int b2 = gm >> 11, sl = gm & 2047;
          size_t base =
              ((size_t)((b2 * 16 + h2) * 128 + (sl >> 4)) * 2 + cc2) * 512 +
              (qk * 16 + (sl & 15)) * 8 + jjq;
          out[base] = f2bf_u((acc[i][j][r] + bv_) * scale);
        }
    }
  }
}

// ---------------------------------------------------------------- o_gemm
// R16: 128x64 tile, BK=64 (16 barriers), 4 waves (2Mx2N), chunked 16x32 LDS
// with the qkv-verified T2 swizzle pair. Compiler-drained dbuf.
__global__ __launch_bounds__(256) void o_gemm(
    const unsigned short* Ctx, const unsigned short* Wo, const float* bo,
    float* out) {
  __shared__ unsigned short As[2 * 2 * 8 * 512];   // 32 KiB
  __shared__ unsigned short Bs[2 * 2 * 4 * 512];   // 16 KiB
  const int p = blockIdx.x;
  const int c = p & 7, j0 = p >> 3;              // j0 0..63
  const int x = j0 & 15, yy = j0 >> 4;           // x 0..15, yy 0..3
  const int y = c * 4 + yy;
  const int m0 = y * 128, n0 = x * 64;
  const int tid = threadIdx.x;
  const int wave = tid >> 6, lane = tid & 63;
  const int lm = lane & 15, quad = lane >> 4;
  const int wm = (wave >> 1) * 64, wn = (wave & 1) * 32;

  // staging: inverse-swizzled global source, linear LDS dest (qkv pattern)
  const int scs = 8 * ((lane & 3) ^ ((lane >> 3) & 3));
  const int srow = lane >> 2;
  const size_t aSrc0 = (size_t)(m0 + wave * 32 + srow) * DM + scs;
  const size_t bSrc0 = (size_t)(n0 + wave * 16 + srow) * DM + scs;
  const int aDst0 = wave * 2 * 512 + lane * 8;   // chunks wave*2, wave*2+1
  const int bDst0 = wave * 512 + lane * 8;       // chunk wave

  // read offsets (swizzled column), chunk = row/16
  const int rcol = (quad * 8) ^ (((lm >> 1) & 3) * 8);
  const int aoff = (wm >> 4) * 512 + lm * 32 + rcol;  // + i*512 + kh*4096 + buf*8192
  const int boff = (wn >> 4) * 512 + lm * 32 + rcol;  // + j*512 + kh*2048 + buf*4096

  f32x4 acc[4][2];
#pragma unroll
  for (int i = 0; i < 4; ++i)
#pragma unroll
    for (int j = 0; j < 2; ++j) {
      f32x4 z = {0.f, 0.f, 0.f, 0.f};
      acc[i][j] = z;
    }

  auto stAB = [&](int buf, int kt) {
#pragma unroll
    for (int kh = 0; kh < 2; ++kh) {
      const unsigned short* sa = Ctx + aSrc0 + (size_t)kt * 64 + kh * 32;
      unsigned short* da = As + buf * 8192 + kh * 4096 + aDst0;
      GLOAD_LDS16(sa, da);
      GLOAD_LDS16(sa + (size_t)16 * DM, da + 512);
      const unsigned short* sb = Wo + bSrc0 + (size_t)kt * 64 + kh * 32;
      GLOAD_LDS16(sb, Bs + buf * 4096 + kh * 2048 + bDst0);
    }
  };

  stAB(0, 0);                                   // stage tile 0 into buf 0
  for (int kt = 0; kt < DM / 64; ++kt) {
    __syncthreads();                            // tile kt resident (drained)
    const int buf = kt & 1;
    if (kt + 1 < DM / 64) stAB(buf ^ 1, kt + 1);
    const unsigned short* Ac = As + buf * 8192;
    const unsigned short* Bc = Bs + buf * 4096;
#pragma unroll
    for (int kh = 0; kh < 2; ++kh) {
      bf16x8 af[4], bf_[2];
#pragma unroll
      for (int i = 0; i < 4; ++i)
        af[i] = *(const bf16x8*)(Ac + kh * 4096 + aoff + i * 512);
#pragma unroll
      for (int j = 0; j < 2; ++j)
        bf_[j] = *(const bf16x8*)(Bc + kh * 2048 + boff + j * 512);
#pragma unroll
      for (int i = 0; i < 4; ++i)
#pragma unroll
        for (int j = 0; j < 2; ++j)
          acc[i][j] = __builtin_amdgcn_mfma_f32_16x16x32_bf16(
              af[i], bf_[j], acc[i][j], 0, 0, 0);
    }
  }

#pragma unroll
  for (int j = 0; j < 2; ++j) {
    int gn = n0 + wn + j * 16 + lm;
    float bv_ = bo[gn];
#pragma unroll
    for (int i = 0; i < 4; ++i)
#pragma unroll
      for (int r = 0; r < 4; ++r) {
        int gm = m0 + wm + i * 16 + quad * 4 + r;
        out[(size_t)gm * DM + gn] = acc[i][j][r] + bv_;
      }
  }
}

// ------------------------------------------------------------- attention
// kt-split waves + K register double-buffer + intra-kt fragment pipeline:
// QK(f+1)/exp(f+1) issued adjacent to PV(f); two alternating per-wave P
// buffers break the write-after-read lgkm serialization. No barriers in
// the hot loop. Grid 1024 = 32 bh x 32 qt, LPT order.
__global__ __launch_bounds__(256, 2) void attn_kernel(
    const unsigned short* __restrict__ Qf, const unsigned short* __restrict__ Kf,
    const unsigned short* __restrict__ Vf, unsigned short* __restrict__ Ctx) {
  __shared__ float Rs[4][64][21];                 // 21-pad reduce buffer
  __shared__ unsigned short Ps[4][2][16 * PSTR];  // 2 P buffers per wave
  const int p = blockIdx.x;
  const int bh = p & 31, qt = 31 - (p >> 5);   // LPT: long blocks first
  const int b = bh >> 4, h = bh & 15;
  const int tid = threadIdx.x, wave = tid >> 6, lane = tid & 63;
  const int lm = lane & 15, quad = lane >> 4;

  const int qbase0 = qt * 64;
  const int nkw = qt + 1;

  const unsigned short* Kb = Kf + (size_t)bh * 256 * 512;
  const unsigned short* Vb = Vf + (size_t)bh * 256 * 512;
  unsigned short* Pw0 = Ps[wave][0];
  unsigned short* Pw1 = Ps[wave][1];

  bf16x8 onesf;
  {
    unsigned short ob[8] = {0x3F80, 0x3F80, 0x3F80, 0x3F80,
                            0x3F80, 0x3F80, 0x3F80, 0x3F80};
    __builtin_memcpy(&onesf, ob, 16);
  }

  // Q for all 4 frags of this block's q-tile
  bf16x8 qf[4][2];
#pragma unroll
  for (int f = 0; f < 4; ++f)
#pragma unroll
    for (int c = 0; c < 2; ++c)
      qf[f][c] = *(const bf16x8*)(Qf +
          ((size_t)(bh * 128 + qt * 4 + f) * 2 + c) * 512 + lane * 8);

  f32x4 oacc[4][4];                            // [frag][a]
#pragma unroll
  for (int f = 0; f < 4; ++f)
#pragma unroll
    for (int a = 0; a < 4; ++a) {
      f32x4 z = {0.f, 0.f, 0.f, 0.f};
      oacc[f][a] = z;
    }
  f32x4 lacc[4];
#pragma unroll
  for (int f = 0; f < 4; ++f) {
    f32x4 z = {0.f, 0.f, 0.f, 0.f};
    lacc[f] = z;
  }

  auto loadK = [&](bf16x8 (&kf)[4][2], int kt) {
#pragma unroll
    for (int ik = 0; ik < 4; ++ik)
#pragma unroll
      for (int c = 0; c < 2; ++c)
        kf[ik][c] = *(const bf16x8*)(Kb +
            ((size_t)(kt * 4 + ik) * 2 + c) * 512 + lane * 8);
  };

  auto qk = [&](f32x4 (&s)[4], bf16x8 (&kf)[4][2], int f) {
#pragma unroll
    for (int ik = 0; ik < 4; ++ik) {
      f32x4 zz = {0.f, 0.f, 0.f, 0.f};
      zz = __builtin_amdgcn_mfma_f32_16x16x32_bf16(kf[ik][0], qf[f][0], zz,
                                                   0, 0, 0);
      s[ik] = __builtin_amdgcn_mfma_f32_16x16x32_bf16(kf[ik][1], qf[f][1], zz,
                                                      0, 0, 0);
    }
  };
  auto maskS = [&](f32x4 (&s)[4], int kt, int f) {
    int qg = qbase0 + f * 16 + lm;
#pragma unroll
    for (int ik = 0; ik < 4; ++ik)
#pragma unroll
      for (int r = 0; r < 4; ++r) {
        int kg = kt * 64 + ik * 16 + quad * 4 + r;
        if (kg > qg) s[ik][r] = -1e30f;
      }
  };
  auto expPack = [&](f32x4 (&s)[4], unsigned short* dst) {
#pragma unroll
    for (int ik = 0; ik < 4; ++ik) {
      float p0 = fexp2(s[ik][0]);
      float p1 = fexp2(s[ik][1]);
      float p2 = fexp2(s[ik][2]);
      float p3 = fexp2(s[ik][3]);
      uint2 w;
      w.x = pack_bf16(p0, p1);
      w.y = pack_bf16(p2, p3);
      *(uint2*)(dst + lm * PSTR + ik * 16 + quad * 4) = w;
    }
  };
  auto pv = [&](int f, const unsigned short* src, bf16x8 (&vf)[4][2]) {
    bf16x8 pf[2];
#pragma unroll
    for (int c = 0; c < 2; ++c)
      pf[c] = *(const bf16x8*)(src + lm * PSTR + c * 32 + quad * 8);
#pragma unroll
    for (int a = 0; a < 4; ++a) {
      oacc[f][a] = __builtin_amdgcn_mfma_f32_16x16x32_bf16(pf[0], vf[a][0],
                                                           oacc[f][a], 0, 0, 0);
      oacc[f][a] = __builtin_amdgcn_mfma_f32_16x16x32_bf16(pf[1], vf[a][1],
                                                           oacc[f][a], 0, 0, 0);
    }
    lacc[f] = __builtin_amdgcn_mfma_f32_16x16x32_bf16(pf[0], onesf, lacc[f],
                                                      0, 0, 0);
    lacc[f] = __builtin_amdgcn_mfma_f32_16x16x32_bf16(pf[1], onesf, lacc[f],
                                                      0, 0, 0);
  };

  auto computeKt = [&](bf16x8 (&kf)[4][2], int kt, bool last) {
    bf16x8 vf[4][2];                           // issue V loads first
#pragma unroll
    for (int a = 0; a < 4; ++a)
#pragma unroll
      for (int c = 0; c < 2; ++c)
        vf[a][c] = *(const bf16x8*)(Vb +
            ((size_t)(kt * 8 + a * 2 + c)) * 512 + lane * 8);

    f32x4 sa[4], sb[4];
    // pipeline: QK/exp of f+1 adjacent to PV of f (independent -> overlap)
    qk(sa, kf, 0); if (last) maskS(sa, kt, 0);
    expPack(sa, Pw0);
    qk(sb, kf, 1); if (last) maskS(sb, kt, 1);
    expPack(sb, Pw1);
    pv(0, Pw0, vf);
    qk(sa, kf, 2); if (last) maskS(sa, kt, 2);
    expPack(sa, Pw0);                          // WAR on Pw0 vs pv(0) reads
    pv(1, Pw1, vf);
    qk(sb, kf, 3); if (last) maskS(sb, kt, 3);
    expPack(sb, Pw1);                          // WAR on Pw1 vs pv(1) reads
    pv(2, Pw0, vf);
    pv(3, Pw1, vf);
  };

  bf16x8 kA[4][2], kB[4][2];
  if (wave < nkw) loadK(kA, wave);
  for (int kt = wave; kt < nkw; kt += 8) {
    if (kt + 4 < nkw) loadK(kB, kt + 4);
    computeKt(kA, kt, kt == nkw - 1);
    if (kt + 4 < nkw) {
      if (kt + 8 < nkw) loadK(kA, kt + 8);
      computeKt(kB, kt + 4, kt + 4 == nkw - 1);
    }
  }

  // cross-wave reduce + store, frag-sequential (reuses one buffer).
  const size_t obase = (size_t)(b * SS) * DM + (size_t)h * DK_;
#pragma unroll
  for (int f = 0; f < 4; ++f) {
    __syncthreads();                           // prev round's reads done
#pragma unroll
    for (int a = 0; a < 4; ++a)
#pragma unroll
      for (int r = 0; r < 4; ++r)
        Rs[wave][lane][a * 4 + r] = oacc[f][a][r];
#pragma unroll
    for (int r = 0; r < 4; ++r)
      Rs[wave][lane][16 + r] = lacc[f][r];
    __syncthreads();
    // wave w stores column block a = w of frag f
#pragma unroll
    for (int r = 0; r < 4; ++r) {
      float ov = Rs[0][lane][wave * 4 + r] + Rs[1][lane][wave * 4 + r] +
                 Rs[2][lane][wave * 4 + r] + Rs[3][lane][wave * 4 + r];
      float lv = Rs[0][lane][16 + r] + Rs[1][lane][16 + r] +
                 Rs[2][lane][16 + r] + Rs[3][lane][16 + r];
      int qg = qbase0 + f * 16 + quad * 4 + r;
      Ctx[obase + (size_t)qg * DM + wave * 16 + lm] = f2bf_u(ov / lv);
    }
  }
}

// ---------------------------------------------------------------- launch
extern "C" void kernel_launch(void* const* d_in, const int* in_sizes, int n_in,
                              void* d_out, int out_size, void* d_ws, size_t ws_size,
                              hipStream_t stream) {
  const float* q = (const float*)d_in[0];
  const float* k = (const float*)d_in[1];
  const float* v = (const float*)d_in[2];
  // d_in[3] = mask (fixed causal tril) — handled analytically
  const float* Wq = (const float*)d_in[4];
  const float* bq = (const float*)d_in[5];
  const float* Wk = (const float*)d_in[6];
  const float* bk = (const float*)d_in[7];
  const float* Wv = (const float*)d_in[8];
  const float* bv = (const float*)d_in[9];
  const float* Wo = (const float*)d_in[10];
  const float* bo = (const float*)d_in[11];

  const size_t NX = (size_t)BB * SS * DM;  // 4194304 shorts
  const size_t NW = (size_t)DM * DM;       // 1048576 shorts
  unsigned short* ws = (unsigned short*)d_ws;
  unsigned short* Qi = ws;
  unsigned short* Ki = Qi + NX;
  unsigned short* Vi = Ki + NX;
  unsigned short* Wqb = Vi + NX;
  unsigned short* Wkb = Wqb + NW;
  unsigned short* Wvb = Wkb + NW;
  unsigned short* Wob = Wvb + NW;
  unsigned short* Qfr = Wob + NW;
  unsigned short* Kfr = Qfr + NX;
  unsigned short* Vfr = Kfr + NX;
  unsigned short* Ctx = Vfr + NX;

  Cvt c;
  c.s[0] = q; c.s[1] = k; c.s[2] = v; c.s[3] = Wq; c.s[4] = Wk; c.s[5] = Wv; c.s[6] = Wo;
  c.d[0] = Qi; c.d[1] = Ki; c.d[2] = Vi; c.d[3] = Wqb; c.d[4] = Wkb; c.d[5] = Wvb; c.d[6] = Wob;
  c.n[0] = c.n[1] = c.n[2] = (int)NX;
  c.n[3] = c.n[4] = c.n[5] = c.n[6] = (int)NW;

  convert_kernel<<<dim3(1024, 7), dim3(256), 0, stream>>>(c);
  qkv_gemm<<<dim3(192), dim3(512), 0, stream>>>(Qi, Ki, Vi, Wqb, Wkb, Wvb,
                                                bq, bk, bv, Qfr, Kfr, Vfr);
  attn_kernel<<<dim3(1024), dim3(256), 0, stream>>>(Qfr, Kfr, Vfr, Ctx);
  o_gemm<<<dim3(512), dim3(256), 0, stream>>>(Ctx, Wob, bo, (float*)d_out);
}